// Round 12
// baseline (123.821 us; speedup 1.0000x reference)
//
#include <hip/hip_runtime.h>

#define NB 16
#define BATCHES 4
#define GXB 64            // blocks per batch; grid (64,4) = 256 blocks
#define BT 1024           // 16 waves/block; launch_bounds(,8) -> VGPR<=64 -> 2 blocks/CU capacity
#define MAGIC 0x7F3A9C51u

typedef unsigned long long ull;

struct WS {
    unsigned int ready;            // MAGIC once tickets+joint are initialized
    unsigned int ticket;           // phase-1 global barrier counter
    unsigned int ticket2;          // finalization election counter
    unsigned int hdrpad[29];       // pad header to 128 B (keep slots off the atomic line)
    float4 slot[BATCHES * GXB];    // per-block {fmin, fmax, mmin, mmax}
    ull joint[BATCHES * 256];      // swizzled fixed-point (x 2^21) joint histogram
};

__global__ __launch_bounds__(BT, 8) void k_mi(const float4* __restrict__ mov,
                                              const float4* __restrict__ fix,
                                              WS* __restrict__ ws, int nvec,
                                              float* __restrict__ out) {
    __shared__ unsigned int ldsJ[16][256];   // per-wave u32 histogram copies (16 KB)
    __shared__ float4 wred[16];
    __shared__ float4 mmbc;
    __shared__ bool isLast;
    __shared__ double shp[256];
    __shared__ double wsum[4];

    int t = threadIdx.x;
    int b = blockIdx.y, bx = blockIdx.x;
    int wid = t >> 6, lane = t & 63;
    unsigned int nblk = gridDim.x * gridDim.y;   // 256

    // block(0,0): zero the global joint accumulators (1024 entries, one per thread)
    if (b == 0 && bx == 0) ws->joint[t] = 0ull;

    #pragma unroll
    for (int i = 0; i < 4; i++) ((unsigned int*)ldsJ)[t + i * BT] = 0u;

    int slice = nvec / GXB;                      // 8192 float4 per array
    const float4* fb = fix + (size_t)b * nvec + (size_t)bx * slice;
    const float4* mb = mov + (size_t)b * nvec + (size_t)bx * slice;

    // ---- phase 1: streaming minmax over this block's slice (8 f4 per array/thread) ----
    float fmn = 3.4e38f, fmx = -3.4e38f, mmn = 3.4e38f, mmx = -3.4e38f;
    #pragma unroll
    for (int k = 0; k < 8; k += 2) {
        float4 a = fb[t + k * BT], c = fb[t + (k + 1) * BT];
        float4 d = mb[t + k * BT], e = mb[t + (k + 1) * BT];
        fmn = fminf(fmn, fminf(fminf(fminf(a.x, a.y), fminf(a.z, a.w)),
                               fminf(fminf(c.x, c.y), fminf(c.z, c.w))));
        fmx = fmaxf(fmx, fmaxf(fmaxf(fmaxf(a.x, a.y), fmaxf(a.z, a.w)),
                               fmaxf(fmaxf(c.x, c.y), fmaxf(c.z, c.w))));
        mmn = fminf(mmn, fminf(fminf(fminf(d.x, d.y), fminf(d.z, d.w)),
                               fminf(fminf(e.x, e.y), fminf(e.z, e.w))));
        mmx = fmaxf(mmx, fmaxf(fmaxf(fmaxf(d.x, d.y), fmaxf(d.z, d.w)),
                               fmaxf(fmaxf(e.x, e.y), fmaxf(e.z, e.w))));
    }
    for (int d = 32; d; d >>= 1) {
        fmn = fminf(fmn, __shfl_xor(fmn, d));
        fmx = fmaxf(fmx, __shfl_xor(fmx, d));
        mmn = fminf(mmn, __shfl_xor(mmn, d));
        mmx = fmaxf(mmx, __shfl_xor(mmx, d));
    }
    if (lane == 0) wred[wid] = make_float4(fmn, fmx, mmn, mmx);
    __syncthreads();

    // ---- device-wide barrier (all 256 blocks co-resident: 16 waves, <=64 VGPR, 18 KB LDS) ----
    if (t == 0) {
        float4 s = wred[0];
        #pragma unroll
        for (int w = 1; w < 16; w++) {
            float4 a = wred[w];
            s.x = fminf(s.x, a.x); s.y = fmaxf(s.y, a.y);
            s.z = fminf(s.z, a.z); s.w = fmaxf(s.w, a.w);
        }
        ws->slot[b * GXB + bx] = s;
        __threadfence();                          // slot (+ block00's joint zeros) device-visible
        if (b == 0 && bx == 0) {
            atomicExch(&ws->ticket, 0u);
            atomicExch(&ws->ticket2, 0u);
            __threadfence();
            atomicExch(&ws->ready, MAGIC);        // publish: tickets/joint initialized
        }
        while (atomicAdd(&ws->ready, 0u) != MAGIC) __builtin_amdgcn_s_sleep(8);
        atomicAdd(&ws->ticket, 1u);
        while (atomicAdd(&ws->ticket, 0u) < nblk) __builtin_amdgcn_s_sleep(8);
    }
    __syncthreads();

    // ---- phase 2: global minmax -> bin this block's (L2/L3-hot) slice ----
    if (t < 64) {
        float4 s = ws->slot[b * GXB + lane];      // 64 slots for this batch
        for (int d = 32; d; d >>= 1) {
            s.x = fminf(s.x, __shfl_xor(s.x, d));
            s.y = fmaxf(s.y, __shfl_xor(s.y, d));
            s.z = fminf(s.z, __shfl_xor(s.z, d));
            s.w = fmaxf(s.w, __shfl_xor(s.w, d));
        }
        if (t == 0) mmbc = s;
    }
    __syncthreads();

    float fbs = (mmbc.y - mmbc.x) * (1.0f / 12.0f);
    float mbs = (mmbc.w - mmbc.z) * (1.0f / 12.0f);
    float finv = 1.0f / fbs;
    float minv = 1.0f / mbs;
    float fofs = __builtin_fmaf(-mmbc.x, finv, 2.0f);
    float mofs = __builtin_fmaf(-mmbc.z, minv, 2.0f);

    unsigned int* myJ = &ldsJ[wid][0];

    auto proc = [&](float fv, float mv) {
        float fterm = __builtin_fmaf(fv, finv, fofs);
        int fi = (int)fterm;
        fi = fi < 2 ? 2 : (fi > NB - 3 ? NB - 3 : fi);
        float mterm = __builtin_fmaf(mv, minv, mofs);
        int mi_ = (int)mterm;
        mi_ = mi_ < 2 ? 2 : (mi_ > NB - 3 ? NB - 3 : mi_);
        float tt = fminf(fmaxf(mterm - (float)mi_, 0.0f), 1.0f);
        float t2 = tt * tt;
        float omt = 1.0f - tt;
        float w0 = omt * omt * omt * (1.0f / 6.0f);                       // off=-1
        float w3 = tt * t2 * (1.0f / 6.0f);                               // off=+2
        float w1 = __builtin_fmaf(__builtin_fmaf(3.0f, tt, -6.0f), t2, 4.0f) * (1.0f / 6.0f);
        float w2 = fmaxf(1.0f - w0 - w1 - w3, 0.0f);                      // off=+1
        // u32 x 2^21; per-wave-copy worst bin: 2048 elem * (2/3)*2^21 = 2.9e9 < 2^32
        int row = fi << 4;
        int s0 = (mi_ - 1 + 5 * fi) & 15;   // bank swizzle
        atomicAdd(myJ + row + s0,              (unsigned int)(w0 * 2097152.0f));
        atomicAdd(myJ + row + ((s0 + 1) & 15), (unsigned int)(w1 * 2097152.0f));
        atomicAdd(myJ + row + ((s0 + 2) & 15), (unsigned int)(w2 * 2097152.0f));
        atomicAdd(myJ + row + ((s0 + 3) & 15), (unsigned int)(w3 * 2097152.0f));
    };

    #pragma unroll
    for (int k = 0; k < 8; k += 2) {
        float4 fA = fb[t + k * BT], fB = fb[t + (k + 1) * BT];
        float4 mA = mb[t + k * BT], mB = mb[t + (k + 1) * BT];
        proc(fA.x, mA.x); proc(fA.y, mA.y); proc(fA.z, mA.z); proc(fA.w, mA.w);
        proc(fB.x, mB.x); proc(fB.y, mB.y); proc(fB.z, mB.z); proc(fB.w, mB.w);
    }
    __syncthreads();

    // flush: sum the 16 wave copies (u64: 16 * 2^32 headroom)
    if (t < 256) {
        ull v = 0;
        #pragma unroll
        for (int c = 0; c < 16; c++) v += (ull)ldsJ[c][t];
        if (v) atomicAdd(&ws->joint[b * 256 + t], v);
    }

    // finalization election: last block computes the MI
    if (t == 0) {
        __threadfence();
        unsigned int done = atomicAdd(&ws->ticket2, 1u);
        isLast = (done == nblk - 1u);
    }
    __syncthreads();
    if (!isLast) return;

    double acc = 0.0;
    for (int bb = 0; bb < BATCHES; ++bb) {
        double v = 0.0;
        ull qq = 0ull;
        if (t < 256) {
            qq = atomicAdd(&ws->joint[bb * 256 + t], 0ull);  // device-scope coherent read
            v = (double)qq;
        }
        double s = v;
        for (int d = 32; d; d >>= 1) s += __shfl_xor(s, d);
        if (t < 256 && (t & 63) == 0) wsum[t >> 6] = s;
        __syncthreads();
        double total = wsum[0] + wsum[1] + wsum[2] + wsum[3];
        double p = (t < 256) ? v / total : 0.0;
        // de-swizzle: slot t = (f, c) holds bin (f, m), m = (c - 5f) & 15
        int f = t >> 4, c = t & 15, m = (c - 5 * f) & 15;
        if (t < 256) shp[f * 16 + m] = p;
        double val = (t < 256 && qq != 0ull) ? p * log(p) : 0.0;
        __syncthreads();
        if (t < 16) {                    // movingPDF: column sums over f
            double mp = 0.0;
            #pragma unroll
            for (int f2 = 0; f2 < 16; ++f2) mp += shp[f2 * 16 + t];
            if (mp > 0.0) val -= mp * log(mp);
        } else if (t < 32) {             // fixedPDF: row sums over m (partition of unity)
            int f2 = t - 16;
            double fp = 0.0;
            #pragma unroll
            for (int m2 = 0; m2 < 16; ++m2) fp += shp[f2 * 16 + m2];
            if (fp > 0.0) val -= fp * log(fp);
        }
        double s2 = val;
        for (int d = 32; d; d >>= 1) s2 += __shfl_xor(s2, d);
        __syncthreads();
        if (t < 256 && (t & 63) == 0) wsum[t >> 6] = s2;
        __syncthreads();
        if (t == 0) acc += wsum[0] + wsum[1] + wsum[2] + wsum[3];
        __syncthreads();
    }
    if (t == 0) {
        out[0] = (float)(-acc / (double)BATCHES);
        __threadfence();
        atomicExch(&ws->ready, 0u);      // leave protocol reset even without re-poison
    }
}

extern "C" void kernel_launch(void* const* d_in, const int* in_sizes, int n_in,
                              void* d_out, int out_size, void* d_ws, size_t ws_size,
                              hipStream_t stream) {
    const float* mov = (const float*)d_in[0];
    const float* fix = (const float*)d_in[1];
    float* out = (float*)d_out;
    WS* ws = (WS*)d_ws;

    int total = in_sizes[0];
    int N = total / BATCHES;      // 128^3
    int nvec = N / 4;

    dim3 grid(GXB, BATCHES);
    k_mi<<<grid, BT, 0, stream>>>((const float4*)mov, (const float4*)fix, ws, nvec, out);
}